// Round 2
// baseline (1271.165 us; speedup 1.0000x reference)
//
#include <hip/hip_runtime.h>
#include <math.h>

#define BDIM 256

// ---------------------------------------------------------------------------
// jax.image.resize (method='bilinear'/'triangle', antialias=True) tap weights.
// sample_f = (o+0.5)*(in/out) - 0.5 ; triangle kernel support scaled by
// max(in/out, 1); weights over valid input indices, renormalized to sum 1.
// Max taps: 8 (4x downscale 256->64).
// ---------------------------------------------------------------------------
__device__ __forceinline__ int resize_taps(int out_n, int o, int in_n,
                                           float* w, int* i0) {
  float inv_scale = (float)in_n / (float)out_n;
  float ks = inv_scale > 1.f ? inv_scale : 1.f;
  float sf = ((float)o + 0.5f) * inv_scale - 0.5f;
  int lo = (int)ceilf(sf - ks);
  int hi = (int)floorf(sf + ks);
  if (lo < 0) lo = 0;
  if (hi > in_n - 1) hi = in_n - 1;
  int n = hi - lo + 1;
  float sum = 0.f;
  for (int k = 0; k < n; ++k) {
    float t = 1.f - fabsf((float)(lo + k) - sf) / ks;
    t = t > 0.f ? t : 0.f;
    w[k] = t;
    sum += t;
  }
  float inv = 1.f / sum;
  for (int k = 0; k < n; ++k) w[k] *= inv;
  *i0 = lo;
  return n;
}

// Generic separable resize, f32 -> f32, NCHW. One thread per output element.
__global__ void k_resize(const float* __restrict__ in, float* __restrict__ out,
                         int C, int Hi, int Wi, int Ho, int Wo) {
  int idx = blockIdx.x * blockDim.x + threadIdx.x;
  int total = C * Ho * Wo;
  if (idx >= total) return;
  int ox = idx % Wo;
  int t = idx / Wo;
  int oy = t % Ho;
  int c = t / Ho;
  float wy[8], wx[8];
  int y0, x0;
  int ny = resize_taps(Ho, oy, Hi, wy, &y0);
  int nx = resize_taps(Wo, ox, Wi, wx, &x0);
  const float* ip = in + (size_t)c * Hi * Wi;
  float acc = 0.f;
  for (int a = 0; a < ny; ++a) {
    const float* row = ip + (size_t)(y0 + a) * Wi + x0;
    float r = 0.f;
    for (int b = 0; b < nx; ++b) r += wx[b] * row[b];
    acc += wy[a] * r;
  }
  out[idx] = acc;
}

// 3x3 same conv, Cin=64 -> Cout=18, pad 1, dil 1. One thread per pixel.
__global__ void k_conv18(const float* __restrict__ in, const float* __restrict__ w,
                         const float* __restrict__ bias, float* __restrict__ out,
                         int H, int W) {
  __shared__ float wl[18 * 64 * 9];
  __shared__ float bl[18];
  for (int i = threadIdx.x; i < 18 * 64 * 9; i += blockDim.x) wl[i] = w[i];
  if (threadIdx.x < 18) bl[threadIdx.x] = bias[threadIdx.x];
  __syncthreads();
  int p = blockIdx.x * blockDim.x + threadIdx.x;
  int HW = H * W;
  if (p >= HW) return;
  int px = p % W, py = p / W;
  float acc[18];
#pragma unroll
  for (int o = 0; o < 18; ++o) acc[o] = bl[o];
  for (int c = 0; c < 64; ++c) {
    const float* ip = in + (size_t)c * HW;
    float nb[9];
#pragma unroll
    for (int ky = 0; ky < 3; ++ky)
#pragma unroll
      for (int kx = 0; kx < 3; ++kx) {
        int yy = py + ky - 1, xx = px + kx - 1;
        nb[ky * 3 + kx] =
            (yy >= 0 && yy < H && xx >= 0 && xx < W) ? ip[yy * W + xx] : 0.f;
      }
#pragma unroll
    for (int k = 0; k < 9; ++k) {
      float v = nb[k];
#pragma unroll
      for (int o = 0; o < 18; ++o) acc[o] += wl[(o * 64 + c) * 9 + k] * v;
    }
  }
#pragma unroll
  for (int o = 0; o < 18; ++o) out[(size_t)o * HW + p] = acc[o];
}

// Deformable 3x3 conv (1 group), Cin=64 -> Cout=16, stride 1, + leaky_relu.
// offsets: 18 channels = (dy,dx) per tap, k-major. One thread per pixel.
__global__ void k_deform(const float* __restrict__ in, const float* __restrict__ off,
                         const float* __restrict__ w, const float* __restrict__ bias,
                         float* __restrict__ out, int H, int W, int pad, int dil) {
  __shared__ float wl[16 * 64 * 9];
  __shared__ float bl[16];
  for (int i = threadIdx.x; i < 16 * 64 * 9; i += blockDim.x) wl[i] = w[i];
  if (threadIdx.x < 16) bl[threadIdx.x] = bias[threadIdx.x];
  __syncthreads();
  int p = blockIdx.x * blockDim.x + threadIdx.x;
  int HW = H * W;
  if (p >= HW) return;
  int px_ = p % W, py_ = p / W;
  float acc[16];
#pragma unroll
  for (int o = 0; o < 16; ++o) acc[o] = bl[o];
#pragma unroll
  for (int k = 0; k < 9; ++k) {
    int ky = k / 3, kx = k % 3;
    float dy = off[(size_t)(2 * k) * HW + p];
    float dx = off[(size_t)(2 * k + 1) * HW + p];
    float py = (float)(py_ - pad + ky * dil) + dy;
    float px = (float)(px_ - pad + kx * dil) + dx;
    float fy0 = floorf(py), fx0 = floorf(px);
    float wy = py - fy0, wx = px - fx0;
    int y0 = (int)fy0, x0 = (int)fx0;
    int y1 = y0 + 1, x1 = x0 + 1;
    bool vy0 = (y0 >= 0 && y0 < H), vy1 = (y1 >= 0 && y1 < H);
    bool vx0 = (x0 >= 0 && x0 < W), vx1 = (x1 >= 0 && x1 < W);
    float w00 = (1.f - wy) * (1.f - wx) * ((vy0 && vx0) ? 1.f : 0.f);
    float w01 = (1.f - wy) * wx * ((vy0 && vx1) ? 1.f : 0.f);
    float w10 = wy * (1.f - wx) * ((vy1 && vx0) ? 1.f : 0.f);
    float w11 = wy * wx * ((vy1 && vx1) ? 1.f : 0.f);
    int cy0 = min(max(y0, 0), H - 1), cy1 = min(max(y1, 0), H - 1);
    int cx0 = min(max(x0, 0), W - 1), cx1 = min(max(x1, 0), W - 1);
    int i00 = cy0 * W + cx0, i01 = cy0 * W + cx1;
    int i10 = cy1 * W + cx0, i11 = cy1 * W + cx1;
    for (int c = 0; c < 64; ++c) {
      const float* ip = in + (size_t)c * HW;
      float s = w00 * ip[i00] + w01 * ip[i01] + w10 * ip[i10] + w11 * ip[i11];
#pragma unroll
      for (int o = 0; o < 16; ++o) acc[o] += wl[(o * 64 + c) * 9 + k] * s;
    }
  }
#pragma unroll
  for (int o = 0; o < 16; ++o) {
    float v = acc[o];
    v = v >= 0.f ? v : 0.01f * v;
    out[(size_t)o * HW + p] = v;
  }
}

__device__ __forceinline__ float gelu_f(float x) {
  return 0.5f * x * (1.f + erff(x * 0.70710678118654752f));
}

__global__ void k_final(const float* __restrict__ a, const float* __restrict__ x1r,
                        const float* __restrict__ x2r, const float* __restrict__ x3r,
                        float* __restrict__ out, int n) {
  int i = blockIdx.x * blockDim.x + threadIdx.x;
  if (i >= n) return;
  float l = gelu_f(x1r[i]);
  float m = gelu_f(a[i] - l);
  float h = gelu_f(x2r[i] - a[i]);
  float s = gelu_f(x3r[i] - x2r[i]);
  out[i] = l;
  out[n + i] = m;
  out[2 * n + i] = h;
  out[3 * n + i] = s;
}

static inline int cdiv(int a, int b) { return (a + b - 1) / b; }

extern "C" void kernel_launch(void* const* d_in, const int* in_sizes, int n_in,
                              void* d_out, int out_size, void* d_ws, size_t ws_size,
                              hipStream_t stream) {
  (void)in_sizes; (void)n_in; (void)out_size; (void)ws_size;
  const float* x = (const float*)d_in[0];
  const float* w_off[4] = {(const float*)d_in[1], (const float*)d_in[5],
                           (const float*)d_in[9], (const float*)d_in[13]};
  const float* b_off[4] = {(const float*)d_in[2], (const float*)d_in[6],
                           (const float*)d_in[10], (const float*)d_in[14]};
  const float* w_c[4] = {(const float*)d_in[3], (const float*)d_in[7],
                         (const float*)d_in[11], (const float*)d_in[15]};
  const float* b_c[4] = {(const float*)d_in[4], (const float*)d_in[8],
                         (const float*)d_in[12], (const float*)d_in[16]};
  float* out = (float*)d_out;

  // Workspace layout (floats), lifetime-aliased; peak 6,684,672 f = 26.7 MB.
  float* ws = (float*)d_ws;
  float* a0 = ws;                 // 65536            [0, 262144) smalls
  float* x1r = ws + 65536;        // 65536
  float* x2r = ws + 131072;       // 65536
  float* x3r = ws + 196608;       // 65536
  float* x3s = ws + 262144;       // 4,194,304        [262144, 4456448)
  //   early aliases inside x3s region (dead before x3s is written):
  float* x1s = ws + 262144;       // 65536
  float* off1 = ws + 327680;      // 18432
  float* a1 = ws + 346112;        // 16384
  float* off0 = ws + 362496;      // 73728   (ends 436224 < 4456448)
  float* off3 = ws + 4456448;     // 1,179,648        [4456448, 5636096)
  float* x2s = ws + 4456448;      // 1,048,576 alias (dead before off3 written)
  float* a3 = ws + 5636096;       // 1,048,576        [5636096, 6684672)
  float* off2 = ws + 5636096;     // 294,912 alias (dead before a3 written)
  float* a2 = ws + 5931008;       // 262,144 alias (ends 6193152)

  // scale 1/2 branch
  k_resize<<<cdiv(64 * 32 * 32, BDIM), BDIM, 0, stream>>>(x, x1s, 64, 64, 64, 32, 32);
  k_conv18<<<cdiv(32 * 32, BDIM), BDIM, 0, stream>>>(x1s, w_off[0], b_off[0], off1, 32, 32);
  k_deform<<<cdiv(32 * 32, BDIM), BDIM, 0, stream>>>(x1s, off1, w_c[3], b_c[3], a1, 32, 32, 4, 4);
  k_resize<<<cdiv(16 * 64 * 64, BDIM), BDIM, 0, stream>>>(a1, x1r, 16, 32, 32, 64, 64);
  // scale 1 branch
  k_conv18<<<cdiv(64 * 64, BDIM), BDIM, 0, stream>>>(x, w_off[1], b_off[1], off0, 64, 64);
  k_deform<<<cdiv(64 * 64, BDIM), BDIM, 0, stream>>>(x, off0, w_c[2], b_c[2], a0, 64, 64, 3, 3);
  // scale 2 branch
  k_resize<<<cdiv(64 * 128 * 128, BDIM), BDIM, 0, stream>>>(x, x2s, 64, 64, 64, 128, 128);
  k_conv18<<<cdiv(128 * 128, BDIM), BDIM, 0, stream>>>(x2s, w_off[2], b_off[2], off2, 128, 128);
  k_deform<<<cdiv(128 * 128, BDIM), BDIM, 0, stream>>>(x2s, off2, w_c[1], b_c[1], a2, 128, 128, 2, 2);
  k_resize<<<cdiv(16 * 64 * 64, BDIM), BDIM, 0, stream>>>(a2, x2r, 16, 128, 128, 64, 64);
  // scale 4 branch (x3s from x2s; then x2s region is reused for off3)
  k_resize<<<cdiv(64 * 256 * 256, BDIM), BDIM, 0, stream>>>(x2s, x3s, 64, 128, 128, 256, 256);
  k_conv18<<<cdiv(256 * 256, BDIM), BDIM, 0, stream>>>(x3s, w_off[3], b_off[3], off3, 256, 256);
  k_deform<<<cdiv(256 * 256, BDIM), BDIM, 0, stream>>>(x3s, off3, w_c[0], b_c[0], a3, 256, 256, 1, 1);
  k_resize<<<cdiv(16 * 64 * 64, BDIM), BDIM, 0, stream>>>(a3, x3r, 16, 256, 256, 64, 64);
  // fuse + gelu
  k_final<<<cdiv(65536, BDIM), BDIM, 0, stream>>>(a0, x1r, x2r, x3r, out, 65536);
}

// Round 3
// 909.155 us; speedup vs baseline: 1.3982x; 1.3982x over previous
//
#include <hip/hip_runtime.h>
#include <math.h>

#define BDIM 256

// ---------------------------------------------------------------------------
// jax.image.resize (method='bilinear'/'triangle', antialias=True) tap weights.
// ---------------------------------------------------------------------------
__device__ __forceinline__ int resize_taps(int out_n, int o, int in_n,
                                           float* w, int* i0) {
  float inv_scale = (float)in_n / (float)out_n;
  float ks = inv_scale > 1.f ? inv_scale : 1.f;
  float sf = ((float)o + 0.5f) * inv_scale - 0.5f;
  int lo = (int)ceilf(sf - ks);
  int hi = (int)floorf(sf + ks);
  if (lo < 0) lo = 0;
  if (hi > in_n - 1) hi = in_n - 1;
  int n = hi - lo + 1;
  float sum = 0.f;
  for (int k = 0; k < n; ++k) {
    float t = 1.f - fabsf((float)(lo + k) - sf) / ks;
    t = t > 0.f ? t : 0.f;
    w[k] = t;
    sum += t;
  }
  float inv = 1.f / sum;
  for (int k = 0; k < n; ++k) w[k] *= inv;
  *i0 = lo;
  return n;
}

__global__ void k_resize(const float* __restrict__ in, float* __restrict__ out,
                         int C, int Hi, int Wi, int Ho, int Wo) {
  int idx = blockIdx.x * blockDim.x + threadIdx.x;
  int total = C * Ho * Wo;
  if (idx >= total) return;
  int ox = idx % Wo;
  int t = idx / Wo;
  int oy = t % Ho;
  int c = t / Ho;
  float wy[8], wx[8];
  int y0, x0;
  int ny = resize_taps(Ho, oy, Hi, wy, &y0);
  int nx = resize_taps(Wo, ox, Wi, wx, &x0);
  const float* ip = in + (size_t)c * Hi * Wi;
  float acc = 0.f;
  for (int a = 0; a < ny; ++a) {
    const float* row = ip + (size_t)(y0 + a) * Wi + x0;
    float r = 0.f;
    for (int b = 0; b < nx; ++b) r += wx[b] * row[b];
    acc += wy[a] * r;
  }
  out[idx] = acc;
}

// ---------------------------------------------------------------------------
// 3x3 conv Cin=64 -> Cout=18, pad 1. Block = 128 pixels x 2 c-halves.
// ---------------------------------------------------------------------------
__global__ __launch_bounds__(256) void k_conv18(
    const float* __restrict__ in, const float* __restrict__ w,
    const float* __restrict__ bias, float* __restrict__ out, int H, int W) {
  __shared__ float wl[18 * 64 * 9];   // 41.5 KB
  __shared__ float bl[18];
  __shared__ float red[128 * 19];     // pad 19 to dodge bank conflicts
  for (int i = threadIdx.x; i < 18 * 64 * 9; i += 256) wl[i] = w[i];
  if (threadIdx.x < 18) bl[threadIdx.x] = bias[threadIdx.x];
  __syncthreads();
  int tid = threadIdx.x;
  int pl = tid & 127;
  int half = tid >> 7;
  int HW = H * W;
  int p = blockIdx.x * 128 + pl;
  int px = p % W, py = p / W;
  float acc[18];
#pragma unroll
  for (int o = 0; o < 18; ++o) acc[o] = half ? 0.f : bl[o];
  const float* ip = in + (size_t)(half * 32) * HW;
  for (int c = 0; c < 32; ++c, ip += HW) {
    float nb[9];
#pragma unroll
    for (int ky = 0; ky < 3; ++ky)
#pragma unroll
      for (int kx = 0; kx < 3; ++kx) {
        int yy = py + ky - 1, xx = px + kx - 1;
        nb[ky * 3 + kx] =
            (yy >= 0 && yy < H && xx >= 0 && xx < W) ? ip[yy * W + xx] : 0.f;
      }
    const float* wc = wl + (size_t)(half * 32 + c) * 9;
#pragma unroll
    for (int o = 0; o < 18; ++o) {
      float a = acc[o];
#pragma unroll
      for (int k = 0; k < 9; ++k) a += wc[o * 576 + k] * nb[k];
      acc[o] = a;
    }
  }
  if (half) {
#pragma unroll
    for (int o = 0; o < 18; ++o) red[pl * 19 + o] = acc[o];
  }
  __syncthreads();
  if (!half) {
#pragma unroll
    for (int o = 0; o < 18; ++o)
      out[(size_t)o * HW + p] = acc[o] + red[pl * 19 + o];
  }
}

// ---------------------------------------------------------------------------
// Deformable 3x3 conv Cin=64 -> Cout=16 + leaky. Block = 128 px x 2 c-halves.
// Tap data (indices + masked bilinear weights) precomputed in registers;
// c-outer / k-inner so each input plane is streamed once.
// ---------------------------------------------------------------------------
__global__ __launch_bounds__(256) void k_deform(
    const float* __restrict__ in, const float* __restrict__ off,
    const float* __restrict__ w, const float* __restrict__ bias,
    float* __restrict__ out, int H, int W, int pad, int dil) {
  __shared__ float wl[16 * 64 * 9];   // 36 KB
  __shared__ float bl[16];
  __shared__ float red[128 * 17];     // 8.5 KB
  for (int i = threadIdx.x; i < 16 * 64 * 9; i += 256) wl[i] = w[i];
  if (threadIdx.x < 16) bl[threadIdx.x] = bias[threadIdx.x];
  __syncthreads();
  int tid = threadIdx.x;
  int pl = tid & 127;
  int half = tid >> 7;
  int HW = H * W;
  int p = blockIdx.x * 128 + pl;
  int px_ = p % W, py_ = p / W;

  int i00[9], i01[9], i10[9], i11[9];
  float w00[9], w01[9], w10[9], w11[9];
#pragma unroll
  for (int k = 0; k < 9; ++k) {
    int ky = k / 3, kx = k % 3;
    float dy = off[(size_t)(2 * k) * HW + p];
    float dx = off[(size_t)(2 * k + 1) * HW + p];
    float py = (float)(py_ - pad + ky * dil) + dy;
    float px = (float)(px_ - pad + kx * dil) + dx;
    float fy0 = floorf(py), fx0 = floorf(px);
    float wy = py - fy0, wx = px - fx0;
    int y0 = (int)fy0, x0 = (int)fx0;
    int y1 = y0 + 1, x1 = x0 + 1;
    bool vy0 = (y0 >= 0 && y0 < H), vy1 = (y1 >= 0 && y1 < H);
    bool vx0 = (x0 >= 0 && x0 < W), vx1 = (x1 >= 0 && x1 < W);
    w00[k] = (1.f - wy) * (1.f - wx) * ((vy0 && vx0) ? 1.f : 0.f);
    w01[k] = (1.f - wy) * wx * ((vy0 && vx1) ? 1.f : 0.f);
    w10[k] = wy * (1.f - wx) * ((vy1 && vx0) ? 1.f : 0.f);
    w11[k] = wy * wx * ((vy1 && vx1) ? 1.f : 0.f);
    int cy0 = min(max(y0, 0), H - 1), cy1 = min(max(y1, 0), H - 1);
    int cx0 = min(max(x0, 0), W - 1), cx1 = min(max(x1, 0), W - 1);
    i00[k] = cy0 * W + cx0;
    i01[k] = cy0 * W + cx1;
    i10[k] = cy1 * W + cx0;
    i11[k] = cy1 * W + cx1;
  }

  float acc[16];
#pragma unroll
  for (int o = 0; o < 16; ++o) acc[o] = half ? 0.f : bl[o];
  const float* ip = in + (size_t)(half * 32) * HW;
  for (int c = 0; c < 32; ++c, ip += HW) {
    float s[9];
#pragma unroll
    for (int k = 0; k < 9; ++k)
      s[k] = w00[k] * ip[i00[k]] + w01[k] * ip[i01[k]] +
             w10[k] * ip[i10[k]] + w11[k] * ip[i11[k]];
    const float* wc = wl + (size_t)(half * 32 + c) * 9;
#pragma unroll
    for (int o = 0; o < 16; ++o) {
      float a = acc[o];
#pragma unroll
      for (int k = 0; k < 9; ++k) a += wc[o * 576 + k] * s[k];
      acc[o] = a;
    }
  }
  if (half) {
#pragma unroll
    for (int o = 0; o < 16; ++o) red[pl * 17 + o] = acc[o];
  }
  __syncthreads();
  if (!half) {
#pragma unroll
    for (int o = 0; o < 16; ++o) {
      float v = acc[o] + red[pl * 17 + o];
      v = v >= 0.f ? v : 0.01f * v;
      out[(size_t)o * HW + p] = v;
    }
  }
}

__device__ __forceinline__ float gelu_f(float x) {
  return 0.5f * x * (1.f + erff(x * 0.70710678118654752f));
}

__global__ void k_final(const float* __restrict__ a, const float* __restrict__ x1r,
                        const float* __restrict__ x2r, const float* __restrict__ x3r,
                        float* __restrict__ out, int n) {
  int i = blockIdx.x * blockDim.x + threadIdx.x;
  if (i >= n) return;
  float l = gelu_f(x1r[i]);
  float m = gelu_f(a[i] - l);
  float h = gelu_f(x2r[i] - a[i]);
  float s = gelu_f(x3r[i] - x2r[i]);
  out[i] = l;
  out[n + i] = m;
  out[2 * n + i] = h;
  out[3 * n + i] = s;
}

static inline int cdiv(int a, int b) { return (a + b - 1) / b; }

extern "C" void kernel_launch(void* const* d_in, const int* in_sizes, int n_in,
                              void* d_out, int out_size, void* d_ws, size_t ws_size,
                              hipStream_t stream) {
  (void)in_sizes; (void)n_in; (void)out_size; (void)ws_size;
  const float* x = (const float*)d_in[0];
  const float* w_off[4] = {(const float*)d_in[1], (const float*)d_in[5],
                           (const float*)d_in[9], (const float*)d_in[13]};
  const float* b_off[4] = {(const float*)d_in[2], (const float*)d_in[6],
                           (const float*)d_in[10], (const float*)d_in[14]};
  const float* w_c[4] = {(const float*)d_in[3], (const float*)d_in[7],
                         (const float*)d_in[11], (const float*)d_in[15]};
  const float* b_c[4] = {(const float*)d_in[4], (const float*)d_in[8],
                         (const float*)d_in[12], (const float*)d_in[16]};
  float* out = (float*)d_out;

  // Workspace layout (floats), lifetime-aliased; peak 6,684,672 f = 26.7 MB.
  float* ws = (float*)d_ws;
  float* a0 = ws;                 // 65536
  float* x1r = ws + 65536;        // 65536
  float* x2r = ws + 131072;       // 65536
  float* x3r = ws + 196608;       // 65536
  float* x3s = ws + 262144;       // 4,194,304
  float* x1s = ws + 262144;       // alias (dead before x3s written)
  float* off1 = ws + 327680;
  float* a1 = ws + 346112;
  float* off0 = ws + 362496;
  float* off3 = ws + 4456448;     // 1,179,648
  float* x2s = ws + 4456448;      // alias (dead before off3 written)
  float* a3 = ws + 5636096;       // 1,048,576
  float* off2 = ws + 5636096;     // alias (dead before a3 written)
  float* a2 = ws + 5931008;       // alias

  // scale 1/2 branch
  k_resize<<<cdiv(64 * 32 * 32, BDIM), BDIM, 0, stream>>>(x, x1s, 64, 64, 64, 32, 32);
  k_conv18<<<32 * 32 / 128, 256, 0, stream>>>(x1s, w_off[0], b_off[0], off1, 32, 32);
  k_deform<<<32 * 32 / 128, 256, 0, stream>>>(x1s, off1, w_c[3], b_c[3], a1, 32, 32, 4, 4);
  k_resize<<<cdiv(16 * 64 * 64, BDIM), BDIM, 0, stream>>>(a1, x1r, 16, 32, 32, 64, 64);
  // scale 1 branch
  k_conv18<<<64 * 64 / 128, 256, 0, stream>>>(x, w_off[1], b_off[1], off0, 64, 64);
  k_deform<<<64 * 64 / 128, 256, 0, stream>>>(x, off0, w_c[2], b_c[2], a0, 64, 64, 3, 3);
  // scale 2 branch
  k_resize<<<cdiv(64 * 128 * 128, BDIM), BDIM, 0, stream>>>(x, x2s, 64, 64, 64, 128, 128);
  k_conv18<<<128 * 128 / 128, 256, 0, stream>>>(x2s, w_off[2], b_off[2], off2, 128, 128);
  k_deform<<<128 * 128 / 128, 256, 0, stream>>>(x2s, off2, w_c[1], b_c[1], a2, 128, 128, 2, 2);
  k_resize<<<cdiv(16 * 64 * 64, BDIM), BDIM, 0, stream>>>(a2, x2r, 16, 128, 128, 64, 64);
  // scale 4 branch
  k_resize<<<cdiv(64 * 256 * 256, BDIM), BDIM, 0, stream>>>(x2s, x3s, 64, 128, 128, 256, 256);
  k_conv18<<<256 * 256 / 128, 256, 0, stream>>>(x3s, w_off[3], b_off[3], off3, 256, 256);
  k_deform<<<256 * 256 / 128, 256, 0, stream>>>(x3s, off3, w_c[0], b_c[0], a3, 256, 256, 1, 1);
  k_resize<<<cdiv(16 * 64 * 64, BDIM), BDIM, 0, stream>>>(a3, x3r, 16, 256, 256, 64, 64);
  // fuse + gelu
  k_final<<<cdiv(65536, BDIM), BDIM, 0, stream>>>(a0, x1r, x2r, x3r, out, 65536);
}

// Round 4
// 682.875 us; speedup vs baseline: 1.8615x; 1.3314x over previous
//
#include <hip/hip_runtime.h>
#include <math.h>

#define BDIM 256

// ---------------------------------------------------------------------------
// jax.image.resize (method='bilinear'/'triangle', antialias=True) tap weights.
// ---------------------------------------------------------------------------
__device__ __forceinline__ int resize_taps(int out_n, int o, int in_n,
                                           float* w, int* i0) {
  float inv_scale = (float)in_n / (float)out_n;
  float ks = inv_scale > 1.f ? inv_scale : 1.f;
  float sf = ((float)o + 0.5f) * inv_scale - 0.5f;
  int lo = (int)ceilf(sf - ks);
  int hi = (int)floorf(sf + ks);
  if (lo < 0) lo = 0;
  if (hi > in_n - 1) hi = in_n - 1;
  int n = hi - lo + 1;
  float sum = 0.f;
  for (int k = 0; k < n; ++k) {
    float t = 1.f - fabsf((float)(lo + k) - sf) / ks;
    t = t > 0.f ? t : 0.f;
    w[k] = t;
    sum += t;
  }
  float inv = 1.f / sum;
  for (int k = 0; k < n; ++k) w[k] *= inv;
  *i0 = lo;
  return n;
}

__global__ void k_resize(const float* __restrict__ in, float* __restrict__ out,
                         int C, int Hi, int Wi, int Ho, int Wo) {
  int idx = blockIdx.x * blockDim.x + threadIdx.x;
  int total = C * Ho * Wo;
  if (idx >= total) return;
  int ox = idx % Wo;
  int t = idx / Wo;
  int oy = t % Ho;
  int c = t / Ho;
  float wy[8], wx[8];
  int y0, x0;
  int ny = resize_taps(Ho, oy, Hi, wy, &y0);
  int nx = resize_taps(Wo, ox, Wi, wx, &x0);
  const float* ip = in + (size_t)c * Hi * Wi;
  float acc = 0.f;
  for (int a = 0; a < ny; ++a) {
    const float* row = ip + (size_t)(y0 + a) * Wi + x0;
    float r = 0.f;
    for (int b = 0; b < nx; ++b) r += wx[b] * row[b];
    acc += wy[a] * r;
  }
  out[idx] = acc;
}

// ---------------------------------------------------------------------------
// 3x3 conv Cin=64 -> Cout=18, pad 1. Block = 512 thr: 128 px x 4 c-groups(16).
// ---------------------------------------------------------------------------
__global__ __launch_bounds__(512) void k_conv18(
    const float* __restrict__ in, const float* __restrict__ w,
    const float* __restrict__ bias, float* __restrict__ out, int H, int W) {
  __shared__ float wl[18 * 64 * 9];     // 41.5 KB
  __shared__ float bl[18];
  __shared__ float red[3 * 128 * 19];   // 29.2 KB (stride 19: conflict-free)
  for (int i = threadIdx.x; i < 18 * 64 * 9; i += 512) wl[i] = w[i];
  if (threadIdx.x < 18) bl[threadIdx.x] = bias[threadIdx.x];
  __syncthreads();
  int tid = threadIdx.x;
  int pl = tid & 127;
  int g = tid >> 7;                      // wave-uniform (128 | wave boundary)
  int HW = H * W;
  int p = blockIdx.x * 128 + pl;
  int px = p % W, py = p / W;
  float acc[18];
#pragma unroll
  for (int o = 0; o < 18; ++o) acc[o] = g ? 0.f : bl[o];
  const float* ip = in + (size_t)(g * 16) * HW;
  for (int c = 0; c < 16; ++c, ip += HW) {
    float nb[9];
#pragma unroll
    for (int ky = 0; ky < 3; ++ky)
#pragma unroll
      for (int kx = 0; kx < 3; ++kx) {
        int yy = py + ky - 1, xx = px + kx - 1;
        nb[ky * 3 + kx] =
            (yy >= 0 && yy < H && xx >= 0 && xx < W) ? ip[yy * W + xx] : 0.f;
      }
    const float* wc = wl + (size_t)(g * 16 + c) * 9;
#pragma unroll
    for (int o = 0; o < 18; ++o) {
      float a = acc[o];
#pragma unroll
      for (int k = 0; k < 9; ++k) a += wc[o * 576 + k] * nb[k];
      acc[o] = a;
    }
  }
  if (g) {
#pragma unroll
    for (int o = 0; o < 18; ++o) red[((g - 1) * 128 + pl) * 19 + o] = acc[o];
  }
  __syncthreads();
  if (!g) {
#pragma unroll
    for (int o = 0; o < 18; ++o)
      out[(size_t)o * HW + p] = acc[o] + red[pl * 19 + o] +
                                red[(128 + pl) * 19 + o] +
                                red[(256 + pl) * 19 + o];
  }
}

// ---------------------------------------------------------------------------
// Deformable 3x3 conv Cin=64 -> Cout=16 + leaky. Block = 512 thr:
// 128 px x 4 c-groups(16). Tap indices+weights in regs; c-outer, k-inner.
// ---------------------------------------------------------------------------
__global__ __launch_bounds__(512) void k_deform(
    const float* __restrict__ in, const float* __restrict__ off,
    const float* __restrict__ w, const float* __restrict__ bias,
    float* __restrict__ out, int H, int W, int pad, int dil) {
  __shared__ float wl[16 * 64 * 9];     // 36 KB
  __shared__ float bl[16];
  __shared__ float red[3 * 128 * 17];   // 25.5 KB (stride 17: conflict-free)
  for (int i = threadIdx.x; i < 16 * 64 * 9; i += 512) wl[i] = w[i];
  if (threadIdx.x < 16) bl[threadIdx.x] = bias[threadIdx.x];
  __syncthreads();
  int tid = threadIdx.x;
  int pl = tid & 127;
  int g = tid >> 7;
  int HW = H * W;
  int p = blockIdx.x * 128 + pl;
  int px_ = p % W, py_ = p / W;

  int i00[9], i01[9], i10[9], i11[9];
  float w00[9], w01[9], w10[9], w11[9];
#pragma unroll
  for (int k = 0; k < 9; ++k) {
    int ky = k / 3, kx = k % 3;
    float dy = off[(size_t)(2 * k) * HW + p];
    float dx = off[(size_t)(2 * k + 1) * HW + p];
    float py = (float)(py_ - pad + ky * dil) + dy;
    float px = (float)(px_ - pad + kx * dil) + dx;
    float fy0 = floorf(py), fx0 = floorf(px);
    float wy = py - fy0, wx = px - fx0;
    int y0 = (int)fy0, x0 = (int)fx0;
    int y1 = y0 + 1, x1 = x0 + 1;
    bool vy0 = (y0 >= 0 && y0 < H), vy1 = (y1 >= 0 && y1 < H);
    bool vx0 = (x0 >= 0 && x0 < W), vx1 = (x1 >= 0 && x1 < W);
    w00[k] = (1.f - wy) * (1.f - wx) * ((vy0 && vx0) ? 1.f : 0.f);
    w01[k] = (1.f - wy) * wx * ((vy0 && vx1) ? 1.f : 0.f);
    w10[k] = wy * (1.f - wx) * ((vy1 && vx0) ? 1.f : 0.f);
    w11[k] = wy * wx * ((vy1 && vx1) ? 1.f : 0.f);
    int cy0 = min(max(y0, 0), H - 1), cy1 = min(max(y1, 0), H - 1);
    int cx0 = min(max(x0, 0), W - 1), cx1 = min(max(x1, 0), W - 1);
    i00[k] = cy0 * W + cx0;
    i01[k] = cy0 * W + cx1;
    i10[k] = cy1 * W + cx0;
    i11[k] = cy1 * W + cx1;
  }

  float acc[16];
#pragma unroll
  for (int o = 0; o < 16; ++o) acc[o] = g ? 0.f : bl[o];
  const float* ip = in + (size_t)(g * 16) * HW;
  for (int c = 0; c < 16; ++c, ip += HW) {
    float s[9];
#pragma unroll
    for (int k = 0; k < 9; ++k)
      s[k] = w00[k] * ip[i00[k]] + w01[k] * ip[i01[k]] +
             w10[k] * ip[i10[k]] + w11[k] * ip[i11[k]];
    const float* wc = wl + (size_t)(g * 16 + c) * 9;
#pragma unroll
    for (int o = 0; o < 16; ++o) {
      float a = acc[o];
#pragma unroll
      for (int k = 0; k < 9; ++k) a += wc[o * 576 + k] * s[k];
      acc[o] = a;
    }
  }
  if (g) {
#pragma unroll
    for (int o = 0; o < 16; ++o) red[((g - 1) * 128 + pl) * 17 + o] = acc[o];
  }
  __syncthreads();
  if (!g) {
#pragma unroll
    for (int o = 0; o < 16; ++o) {
      float v = acc[o] + red[pl * 17 + o] + red[(128 + pl) * 17 + o] +
                red[(256 + pl) * 17 + o];
      v = v >= 0.f ? v : 0.01f * v;
      out[(size_t)o * HW + p] = v;
    }
  }
}

__device__ __forceinline__ float gelu_f(float x) {
  return 0.5f * x * (1.f + erff(x * 0.70710678118654752f));
}

__global__ void k_final(const float* __restrict__ a, const float* __restrict__ x1r,
                        const float* __restrict__ x2r, const float* __restrict__ x3r,
                        float* __restrict__ out, int n) {
  int i = blockIdx.x * blockDim.x + threadIdx.x;
  if (i >= n) return;
  float l = gelu_f(x1r[i]);
  float m = gelu_f(a[i] - l);
  float h = gelu_f(x2r[i] - a[i]);
  float s = gelu_f(x3r[i] - x2r[i]);
  out[i] = l;
  out[n + i] = m;
  out[2 * n + i] = h;
  out[3 * n + i] = s;
}

static inline int cdiv(int a, int b) { return (a + b - 1) / b; }

extern "C" void kernel_launch(void* const* d_in, const int* in_sizes, int n_in,
                              void* d_out, int out_size, void* d_ws, size_t ws_size,
                              hipStream_t stream) {
  (void)in_sizes; (void)n_in; (void)out_size; (void)ws_size;
  const float* x = (const float*)d_in[0];
  const float* w_off[4] = {(const float*)d_in[1], (const float*)d_in[5],
                           (const float*)d_in[9], (const float*)d_in[13]};
  const float* b_off[4] = {(const float*)d_in[2], (const float*)d_in[6],
                           (const float*)d_in[10], (const float*)d_in[14]};
  const float* w_c[4] = {(const float*)d_in[3], (const float*)d_in[7],
                         (const float*)d_in[11], (const float*)d_in[15]};
  const float* b_c[4] = {(const float*)d_in[4], (const float*)d_in[8],
                         (const float*)d_in[12], (const float*)d_in[16]};
  float* out = (float*)d_out;

  // Workspace layout (floats), lifetime-aliased; peak 6,684,672 f = 26.7 MB.
  float* ws = (float*)d_ws;
  float* a0 = ws;                 // 65536
  float* x1r = ws + 65536;        // 65536
  float* x2r = ws + 131072;       // 65536
  float* x3r = ws + 196608;       // 65536
  float* x3s = ws + 262144;       // 4,194,304
  float* x1s = ws + 262144;       // alias (dead before x3s written)
  float* off1 = ws + 327680;
  float* a1 = ws + 346112;
  float* off0 = ws + 362496;
  float* off3 = ws + 4456448;     // 1,179,648
  float* x2s = ws + 4456448;      // alias (dead before off3 written)
  float* a3 = ws + 5636096;       // 1,048,576
  float* off2 = ws + 5636096;     // alias (dead before a3 written)
  float* a2 = ws + 5931008;       // alias

  // scale 1/2 branch
  k_resize<<<cdiv(64 * 32 * 32, BDIM), BDIM, 0, stream>>>(x, x1s, 64, 64, 64, 32, 32);
  k_conv18<<<32 * 32 / 128, 512, 0, stream>>>(x1s, w_off[0], b_off[0], off1, 32, 32);
  k_deform<<<32 * 32 / 128, 512, 0, stream>>>(x1s, off1, w_c[3], b_c[3], a1, 32, 32, 4, 4);
  k_resize<<<cdiv(16 * 64 * 64, BDIM), BDIM, 0, stream>>>(a1, x1r, 16, 32, 32, 64, 64);
  // scale 1 branch
  k_conv18<<<64 * 64 / 128, 512, 0, stream>>>(x, w_off[1], b_off[1], off0, 64, 64);
  k_deform<<<64 * 64 / 128, 512, 0, stream>>>(x, off0, w_c[2], b_c[2], a0, 64, 64, 3, 3);
  // scale 2 branch
  k_resize<<<cdiv(64 * 128 * 128, BDIM), BDIM, 0, stream>>>(x, x2s, 64, 64, 64, 128, 128);
  k_conv18<<<128 * 128 / 128, 512, 0, stream>>>(x2s, w_off[2], b_off[2], off2, 128, 128);
  k_deform<<<128 * 128 / 128, 512, 0, stream>>>(x2s, off2, w_c[1], b_c[1], a2, 128, 128, 2, 2);
  k_resize<<<cdiv(16 * 64 * 64, BDIM), BDIM, 0, stream>>>(a2, x2r, 16, 128, 128, 64, 64);
  // scale 4 branch
  k_resize<<<cdiv(64 * 256 * 256, BDIM), BDIM, 0, stream>>>(x2s, x3s, 64, 128, 128, 256, 256);
  k_conv18<<<256 * 256 / 128, 512, 0, stream>>>(x3s, w_off[3], b_off[3], off3, 256, 256);
  k_deform<<<256 * 256 / 128, 512, 0, stream>>>(x3s, off3, w_c[0], b_c[0], a3, 256, 256, 1, 1);
  k_resize<<<cdiv(16 * 64 * 64, BDIM), BDIM, 0, stream>>>(a3, x3r, 16, 256, 256, 64, 64);
  // fuse + gelu
  k_final<<<cdiv(65536, BDIM), BDIM, 0, stream>>>(a0, x1r, x2r, x3r, out, 65536);
}

// Round 5
// 422.619 us; speedup vs baseline: 3.0078x; 1.6158x over previous
//
#include <hip/hip_runtime.h>
#include <math.h>

#define BDIM 256

// ---------------------------------------------------------------------------
// jax.image.resize (bilinear/triangle, antialias=True) tap weights.
// ---------------------------------------------------------------------------
__device__ __forceinline__ int resize_taps(int out_n, int o, int in_n,
                                           float* w, int* i0) {
  float inv_scale = (float)in_n / (float)out_n;
  float ks = inv_scale > 1.f ? inv_scale : 1.f;
  float sf = ((float)o + 0.5f) * inv_scale - 0.5f;
  int lo = (int)ceilf(sf - ks);
  int hi = (int)floorf(sf + ks);
  if (lo < 0) lo = 0;
  if (hi > in_n - 1) hi = in_n - 1;
  int n = hi - lo + 1;
  float sum = 0.f;
  for (int k = 0; k < n; ++k) {
    float t = 1.f - fabsf((float)(lo + k) - sf) / ks;
    t = t > 0.f ? t : 0.f;
    w[k] = t;
    sum += t;
  }
  float inv = 1.f / sum;
  for (int k = 0; k < n; ++k) w[k] *= inv;
  *i0 = lo;
  return n;
}

__global__ void k_resize(const float* __restrict__ in, float* __restrict__ out,
                         int C, int Hi, int Wi, int Ho, int Wo) {
  int idx = blockIdx.x * blockDim.x + threadIdx.x;
  int total = C * Ho * Wo;
  if (idx >= total) return;
  int ox = idx % Wo;
  int t = idx / Wo;
  int oy = t % Ho;
  int c = t / Ho;
  float wy[8], wx[8];
  int y0, x0;
  int ny = resize_taps(Ho, oy, Hi, wy, &y0);
  int nx = resize_taps(Wo, ox, Wi, wx, &x0);
  const float* ip = in + (size_t)c * Hi * Wi;
  float acc = 0.f;
  for (int a = 0; a < ny; ++a) {
    const float* row = ip + (size_t)(y0 + a) * Wi + x0;
    float r = 0.f;
    for (int b = 0; b < nx; ++b) r += wx[b] * row[b];
    acc += wy[a] * r;
  }
  out[idx] = acc;
}

// ---------------------------------------------------------------------------
// Weight transpose prep: deform w_c[i] (16,64,3,3) -> wT[c][o][k] 9216 fl each
// at dst + i*9216; conv w_off[i] (18,64,3,3) -> wT[c][o][k] 10368 fl each at
// dst + 36864 + i*10368.
// ---------------------------------------------------------------------------
__global__ void k_wtrans(const float* __restrict__ d0, const float* __restrict__ d1,
                         const float* __restrict__ d2, const float* __restrict__ d3,
                         const float* __restrict__ c0, const float* __restrict__ c1,
                         const float* __restrict__ c2, const float* __restrict__ c3,
                         float* __restrict__ dst) {
  int idx = blockIdx.x * 256 + threadIdx.x;
  if (idx < 36864) {
    int i = idx / 9216, r = idx % 9216;
    int c = r / 144, rem = r % 144, o = rem / 9, k = rem % 9;
    const float* s = i == 0 ? d0 : i == 1 ? d1 : i == 2 ? d2 : d3;
    dst[idx] = s[(o * 64 + c) * 9 + k];
  } else if (idx < 36864 + 41472) {
    int j = idx - 36864;
    int i = j / 10368, r = j % 10368;
    int c = r / 162, rem = r % 162, o = rem / 9, k = rem % 9;
    const float* s = i == 0 ? c0 : i == 1 ? c1 : i == 2 ? c2 : c3;
    dst[idx] = s[(o * 64 + c) * 9 + k];
  }
}

// ---------------------------------------------------------------------------
// 3x3 conv Cin=64 -> Cout=18, pad 1. Block = 4 waves; wave g handles channels
// [16g,16g+16) for the block's 64 pixels (lane = pixel). Weights via uniform
// scalar loads from wT[c][o][k]; cross-wave reduce through LDS.
// ---------------------------------------------------------------------------
__global__ __launch_bounds__(256) void k_conv18(
    const float* __restrict__ in, const float* __restrict__ wT,
    const float* __restrict__ bias, float* __restrict__ out, int H, int W) {
  __shared__ float red[3 * 64 * 19];
  int tid = threadIdx.x;
  int lane = tid & 63;
  int g = tid >> 6;
  int gu = __builtin_amdgcn_readfirstlane(g);
  int HW = H * W;
  int p = blockIdx.x * 64 + lane;
  int px = p % W, py = p / W;
  float acc[18];
#pragma unroll
  for (int o = 0; o < 18; ++o) acc[o] = 0.f;
  const float* ip = in + (size_t)(gu * 16) * HW;
  const float* wbase = wT + (size_t)(gu * 16) * 162;
  for (int c = 0; c < 16; ++c, ip += HW, wbase += 162) {
    float nb[9];
#pragma unroll
    for (int ky = 0; ky < 3; ++ky)
#pragma unroll
      for (int kx = 0; kx < 3; ++kx) {
        int yy = py + ky - 1, xx = px + kx - 1;
        nb[ky * 3 + kx] =
            (yy >= 0 && yy < H && xx >= 0 && xx < W) ? ip[yy * W + xx] : 0.f;
      }
#pragma unroll
    for (int o = 0; o < 18; ++o) {
      float a = acc[o];
#pragma unroll
      for (int k = 0; k < 9; ++k) a += wbase[o * 9 + k] * nb[k];
      acc[o] = a;
    }
  }
  if (g) {
#pragma unroll
    for (int o = 0; o < 18; ++o) red[((g - 1) * 64 + lane) * 19 + o] = acc[o];
  }
  __syncthreads();
  if (!g) {
#pragma unroll
    for (int o = 0; o < 18; ++o)
      out[(size_t)o * HW + p] = acc[o] + bias[o] + red[lane * 19 + o] +
                                red[(64 + lane) * 19 + o] +
                                red[(128 + lane) * 19 + o];
  }
}

// ---------------------------------------------------------------------------
// Deformable 3x3 conv Cin=64 -> Cout=16 + leaky. Block = 4 waves; wave g owns
// channels [16g,16g+16) for 64 pixels (lane = pixel). Tap state: 2 row bases +
// 4 edge-transformed weights (x-clamp folded into weight permutation so each
// row needs one f32 pair at [a, a+1]). Weights via uniform s_loads.
// ---------------------------------------------------------------------------
__global__ __launch_bounds__(256) void k_deform(
    const float* __restrict__ in, const float* __restrict__ off,
    const float* __restrict__ wT, const float* __restrict__ bias,
    float* __restrict__ out, int H, int W, int pad, int dil) {
  __shared__ float red[3 * 64 * 17];
  int tid = threadIdx.x;
  int lane = tid & 63;
  int g = tid >> 6;
  int gu = __builtin_amdgcn_readfirstlane(g);
  int HW = H * W;
  int p = blockIdx.x * 64 + lane;
  int px_ = p % W, py_ = p / W;

  int A0[9], A1[9];
  float W00[9], W01[9], W10[9], W11[9];
#pragma unroll
  for (int k = 0; k < 9; ++k) {
    int ky = k / 3, kx = k % 3;
    float dy = off[(size_t)(2 * k) * HW + p];
    float dx = off[(size_t)(2 * k + 1) * HW + p];
    float py = (float)(py_ - pad + ky * dil) + dy;
    float px = (float)(px_ - pad + kx * dil) + dx;
    float fy0 = floorf(py), fx0 = floorf(px);
    float wy = py - fy0, wx = px - fx0;
    int y0 = (int)fy0, x0 = (int)fx0;
    // row weights carry y-validity and the x-window gate
    float xg = (x0 >= -1 && x0 <= W - 1) ? 1.f : 0.f;
    float r0 = (1.f - wy) * ((y0 >= 0 && y0 < H) ? xg : 0.f);
    float r1 = wy * ((y0 + 1 >= 0 && y0 + 1 < H) ? xg : 0.f);
    float cl = 1.f - wx, cr = wx;
    bool lo = x0 < 0, hi = x0 > W - 2;   // exclusive (W >= 2)
    // fold x-clamp into weight permutation: value pair is [ip[a], ip[a+1]]
    W00[k] = lo ? r0 * cr : (hi ? 0.f : r0 * cl);
    W01[k] = lo ? 0.f : (hi ? r0 * cl : r0 * cr);
    W10[k] = lo ? r1 * cr : (hi ? 0.f : r1 * cl);
    W11[k] = lo ? 0.f : (hi ? r1 * cl : r1 * cr);
    int ax = min(max(x0, 0), W - 2);
    int cy0 = min(max(y0, 0), H - 1);
    int cy1 = min(max(y0 + 1, 0), H - 1);
    A0[k] = cy0 * W + ax;
    A1[k] = cy1 * W + ax;
  }

  float acc[16];
#pragma unroll
  for (int o = 0; o < 16; ++o) acc[o] = 0.f;
  const float* ip = in + (size_t)(gu * 16) * HW;
  const float* wbase = wT + (size_t)(gu * 16) * 144;
  for (int c = 0; c < 16; ++c, ip += HW, wbase += 144) {
    float s[9];
#pragma unroll
    for (int k = 0; k < 9; ++k) {
      const float* r0p = ip + A0[k];
      const float* r1p = ip + A1[k];
      s[k] = W00[k] * r0p[0] + W01[k] * r0p[1] +
             W10[k] * r1p[0] + W11[k] * r1p[1];
    }
#pragma unroll
    for (int o = 0; o < 16; ++o) {
      float a = acc[o];
#pragma unroll
      for (int k = 0; k < 9; ++k) a += wbase[o * 9 + k] * s[k];
      acc[o] = a;
    }
  }
  if (g) {
#pragma unroll
    for (int o = 0; o < 16; ++o) red[((g - 1) * 64 + lane) * 17 + o] = acc[o];
  }
  __syncthreads();
  if (!g) {
#pragma unroll
    for (int o = 0; o < 16; ++o) {
      float v = acc[o] + bias[o] + red[lane * 17 + o] +
                red[(64 + lane) * 17 + o] + red[(128 + lane) * 17 + o];
      v = v >= 0.f ? v : 0.01f * v;
      out[(size_t)o * HW + p] = v;
    }
  }
}

__device__ __forceinline__ float gelu_f(float x) {
  return 0.5f * x * (1.f + erff(x * 0.70710678118654752f));
}

__global__ void k_final(const float* __restrict__ a, const float* __restrict__ x1r,
                        const float* __restrict__ x2r, const float* __restrict__ x3r,
                        float* __restrict__ out, int n) {
  int i = blockIdx.x * blockDim.x + threadIdx.x;
  if (i >= n) return;
  float l = gelu_f(x1r[i]);
  float m = gelu_f(a[i] - l);
  float h = gelu_f(x2r[i] - a[i]);
  float s = gelu_f(x3r[i] - x2r[i]);
  out[i] = l;
  out[n + i] = m;
  out[2 * n + i] = h;
  out[3 * n + i] = s;
}

static inline int cdiv(int a, int b) { return (a + b - 1) / b; }

extern "C" void kernel_launch(void* const* d_in, const int* in_sizes, int n_in,
                              void* d_out, int out_size, void* d_ws, size_t ws_size,
                              hipStream_t stream) {
  (void)in_sizes; (void)n_in; (void)out_size; (void)ws_size;
  const float* x = (const float*)d_in[0];
  const float* w_off[4] = {(const float*)d_in[1], (const float*)d_in[5],
                           (const float*)d_in[9], (const float*)d_in[13]};
  const float* b_off[4] = {(const float*)d_in[2], (const float*)d_in[6],
                           (const float*)d_in[10], (const float*)d_in[14]};
  const float* w_c[4] = {(const float*)d_in[3], (const float*)d_in[7],
                         (const float*)d_in[11], (const float*)d_in[15]};
  const float* b_c[4] = {(const float*)d_in[4], (const float*)d_in[8],
                         (const float*)d_in[12], (const float*)d_in[16]};
  float* out = (float*)d_out;

  // Workspace layout (floats), lifetime-aliased; peak ~27.1 MB.
  float* ws = (float*)d_ws;
  float* a0 = ws;                 // 65536
  float* x1r = ws + 65536;        // 65536
  float* x2r = ws + 131072;       // 65536
  float* x3r = ws + 196608;       // 65536
  float* x3s = ws + 262144;       // 4,194,304
  float* x1s = ws + 262144;       // alias (dead before x3s written)
  float* off1 = ws + 327680;
  float* a1 = ws + 346112;
  float* off0 = ws + 362496;
  float* off3 = ws + 4456448;     // 1,179,648
  float* x2s = ws + 4456448;      // alias (dead before off3 written)
  float* a3 = ws + 5636096;       // 1,048,576
  float* off2 = ws + 5636096;     // alias (dead before a3 written)
  float* a2 = ws + 5931008;       // alias
  float* wT = ws + 6684672;       // 78,336 transposed weights
  float* wTd[4] = {wT, wT + 9216, wT + 18432, wT + 27648};
  float* wTc[4] = {wT + 36864, wT + 47232, wT + 57600, wT + 67968};

  // weight transpose prep (one launch)
  k_wtrans<<<cdiv(78336, 256), 256, 0, stream>>>(
      w_c[0], w_c[1], w_c[2], w_c[3], w_off[0], w_off[1], w_off[2], w_off[3], wT);

  // scale 1/2 branch
  k_resize<<<cdiv(64 * 32 * 32, BDIM), BDIM, 0, stream>>>(x, x1s, 64, 64, 64, 32, 32);
  k_conv18<<<32 * 32 / 64, 256, 0, stream>>>(x1s, wTc[0], b_off[0], off1, 32, 32);
  k_deform<<<32 * 32 / 64, 256, 0, stream>>>(x1s, off1, wTd[3], b_c[3], a1, 32, 32, 4, 4);
  k_resize<<<cdiv(16 * 64 * 64, BDIM), BDIM, 0, stream>>>(a1, x1r, 16, 32, 32, 64, 64);
  // scale 1 branch
  k_conv18<<<64 * 64 / 64, 256, 0, stream>>>(x, wTc[1], b_off[1], off0, 64, 64);
  k_deform<<<64 * 64 / 64, 256, 0, stream>>>(x, off0, wTd[2], b_c[2], a0, 64, 64, 3, 3);
  // scale 2 branch
  k_resize<<<cdiv(64 * 128 * 128, BDIM), BDIM, 0, stream>>>(x, x2s, 64, 64, 64, 128, 128);
  k_conv18<<<128 * 128 / 64, 256, 0, stream>>>(x2s, wTc[2], b_off[2], off2, 128, 128);
  k_deform<<<128 * 128 / 64, 256, 0, stream>>>(x2s, off2, wTd[1], b_c[1], a2, 128, 128, 2, 2);
  k_resize<<<cdiv(16 * 64 * 64, BDIM), BDIM, 0, stream>>>(a2, x2r, 16, 128, 128, 64, 64);
  // scale 4 branch
  k_resize<<<cdiv(64 * 256 * 256, BDIM), BDIM, 0, stream>>>(x2s, x3s, 64, 128, 128, 256, 256);
  k_conv18<<<256 * 256 / 64, 256, 0, stream>>>(x3s, wTc[3], b_off[3], off3, 256, 256);
  k_deform<<<256 * 256 / 64, 256, 0, stream>>>(x3s, off3, wTd[0], b_c[0], a3, 256, 256, 1, 1);
  k_resize<<<cdiv(16 * 64 * 64, BDIM), BDIM, 0, stream>>>(a3, x3r, 16, 256, 256, 64, 64);
  // fuse + gelu
  k_final<<<cdiv(65536, BDIM), BDIM, 0, stream>>>(a0, x1r, x2r, x3r, out, 65536);
}